// Round 9
// baseline (953.941 us; speedup 1.0000x reference)
//
#include <hip/hip_runtime.h>
#include <hip/hip_bf16.h>

// IndRNN forward, 2 layers. B=64 T=2048 I=256 H=512.
// Tier A (ws >= 513.5MB), TILED layout [b][hb=8][t=2048][j=64]:
//   CONV:  W0,W1 -> bf16 hi/lo tables
//   GEMM0: pre0 = x @ W0^T + b0  -> pre0 TILED fp32 (ws+0)
//   SCAN0: tiled scan, contiguous 4KB chunks; writes packed u32 (bf16hi|lo)
//          A1p TILED (ws+256MB)
//   GEMM1: A1p @ W1^T + b1 -> pre1 TILED fp32 (aliases ws+0; pre0 dead)
//   SCAN1: tiled read, writes d_out row-major [b][t][h]
// Scan pipeline: 4 x global_load_lds dwordx4 per 16-t chunk + 16 stores
// = 20 vmem ops/iter -> vmcnt(60) = true 3-chunk lookahead (see derivation).
// Tier B (small ws): round-8 proven fallback (MODE0 GEMMs + strided scan).

#define BB 64
#define TT 2048
#define II 256
#define HH 512
#define MM (BB * TT)  // 131072

typedef __attribute__((ext_vector_type(8))) short bf16x8;
typedef __attribute__((ext_vector_type(8))) unsigned short u16x8;
typedef __attribute__((ext_vector_type(4))) float f32x4;

__device__ inline unsigned short bf16_rne(float f) {
  unsigned u = __builtin_bit_cast(unsigned, f);
  u += 0x7FFFu + ((u >> 16) & 1u);
  return (unsigned short)(u >> 16);
}
__device__ inline float bf16_val(unsigned short h) {
  unsigned u = ((unsigned)h) << 16;
  return __builtin_bit_cast(float, u);
}

typedef __attribute__((address_space(1))) const void GASV;
typedef __attribute__((address_space(3))) void LASV;
__device__ inline void gload_lds4(const float* g, float* l) {
  __builtin_amdgcn_global_load_lds((GASV*)g, (LASV*)l, 4, 0, 0);
}
__device__ inline void gload_lds16(const float* g, float* l) {
  __builtin_amdgcn_global_load_lds((GASV*)g, (LASV*)l, 16, 0, 0);
}

// ---------------------------------------------------------------------------
// bf16x3 MFMA GEMM: C[M x 512] = A[M x K] * W[512 x K]^T + bias
// 128x128 tile, BK=32, 4 waves (2x2 of 64x64). LDS rows padded to 40 bf16.
// MODE 0: A fp32 row-major + W fp32 (both converted in-kernel)   [Tier B]
// MODE 1: A fp32 row-major + W pre-converted bf16 hi/lo          [GEMM0]
// MODE 3: A packed-u32 TILED (hi<<16|lo) + W bf16 hi/lo          [GEMM1]
// OUTTILED: C written to TILED fp32 layout; else row-major.
// XCD-co-locating bid swizzle (A-panel sharers land on one XCD).
// ---------------------------------------------------------------------------
template <int K, int MODE, bool OUTTILED>
__global__ __launch_bounds__(256) void gemm_mfma(
    const float* __restrict__ Af, const unsigned* __restrict__ Apg,
    const float* __restrict__ Wf, const unsigned short* __restrict__ Whg,
    const unsigned short* __restrict__ Wlg, const float* __restrict__ bias,
    float* __restrict__ C) {
  constexpr int BM = 128, BN = 128, BK = 32;
  constexpr int LDT = 40;
  __shared__ unsigned short Ah[BM * LDT], Al[BM * LDT];
  __shared__ unsigned short Bh[BN * LDT], Bl[BN * LDT];

  const int bid = blockIdx.x;  // 0..4095
  const int xcd = bid & 7;
  const int local = bid >> 3;
  const int mb = xcd * (MM / BM / 8) + (local >> 2);
  const int nb = local & 3;
  const int m0 = mb * BM, n0 = nb * BN;

  const int tid = threadIdx.x;
  const int lane = tid & 63;
  const int wave = tid >> 6;
  const int wr = wave >> 1, wc = wave & 1;
  const int lrow = lane & 15, lkg = lane >> 4;

  f32x4 acc[4][4] = {};

  const int srow = tid >> 1;        // staged row (0..127)
  const int skq = (tid & 1) * 4;    // float4 index (fp32 A path)
  const int skq8 = (tid & 1) * 16;  // element index (bf16/packed paths)

  for (int kt = 0; kt < K; kt += BK) {
    // ---- global loads (issued before barrier; no LDS dependency)
    float4 av[4], wv[4];
    bf16x8 w8[4];
    uint4 q[4];
    if constexpr (MODE == 3) {
      const int m = m0 + srow;
      const int b = m >> 11, t = m & 2047;
      const int kk = kt + skq8;
      const unsigned* ap =
          Apg + ((size_t)(b * 8 + (kk >> 6)) * TT + t) * 64 + (kk & 63);
#pragma unroll
      for (int s = 0; s < 4; ++s) q[s] = *(const uint4*)(ap + s * 4);
    } else {
      const float4* Aq = (const float4*)(Af + (size_t)(m0 + srow) * K + kt) + skq;
#pragma unroll
      for (int s = 0; s < 4; ++s) av[s] = Aq[s];
    }
    if constexpr (MODE >= 1) {
      const size_t ro = (size_t)(n0 + srow) * K + kt + skq8;
      w8[0] = *(const bf16x8*)(Whg + ro);
      w8[1] = *(const bf16x8*)(Whg + ro + 8);
      w8[2] = *(const bf16x8*)(Wlg + ro);
      w8[3] = *(const bf16x8*)(Wlg + ro + 8);
    } else {
      const float4* Wq = (const float4*)(Wf + (size_t)(n0 + srow) * K + kt) + skq;
#pragma unroll
      for (int s = 0; s < 4; ++s) wv[s] = Wq[s];
    }

    __syncthreads();  // previous compute's LDS reads done

    // ---- A tile to LDS
    if constexpr (MODE == 3) {
      const unsigned qq[16] = {q[0].x, q[0].y, q[0].z, q[0].w, q[1].x, q[1].y,
                               q[1].z, q[1].w, q[2].x, q[2].y, q[2].z, q[2].w,
                               q[3].x, q[3].y, q[3].z, q[3].w};
      u16x8 ha, hb2, la, lb;
#pragma unroll
      for (int e = 0; e < 8; ++e) {
        ha[e] = (unsigned short)(qq[e] >> 16);
        la[e] = (unsigned short)(qq[e] & 0xFFFFu);
        hb2[e] = (unsigned short)(qq[e + 8] >> 16);
        lb[e] = (unsigned short)(qq[e + 8] & 0xFFFFu);
      }
      *(u16x8*)&Ah[srow * LDT + skq8] = ha;
      *(u16x8*)&Ah[srow * LDT + skq8 + 8] = hb2;
      *(u16x8*)&Al[srow * LDT + skq8] = la;
      *(u16x8*)&Al[srow * LDT + skq8 + 8] = lb;
    } else {
#pragma unroll
      for (int s = 0; s < 4; ++s) {
        const int kk = (skq + s) * 4;
        const float fa[4] = {av[s].x, av[s].y, av[s].z, av[s].w};
        ushort4 ah4, al4;
        unsigned short* pah = (unsigned short*)&ah4;
        unsigned short* pal = (unsigned short*)&al4;
#pragma unroll
        for (int e = 0; e < 4; ++e) {
          const unsigned short h1 = bf16_rne(fa[e]);
          pah[e] = h1;
          pal[e] = bf16_rne(fa[e] - bf16_val(h1));
        }
        *(ushort4*)&Ah[srow * LDT + kk] = ah4;
        *(ushort4*)&Al[srow * LDT + kk] = al4;
      }
    }
    // ---- W tile to LDS
    if constexpr (MODE >= 1) {
      *(bf16x8*)&Bh[srow * LDT + skq8] = w8[0];
      *(bf16x8*)&Bh[srow * LDT + skq8 + 8] = w8[1];
      *(bf16x8*)&Bl[srow * LDT + skq8] = w8[2];
      *(bf16x8*)&Bl[srow * LDT + skq8 + 8] = w8[3];
    } else {
#pragma unroll
      for (int s = 0; s < 4; ++s) {
        const int kk = (skq + s) * 4;
        const float fw[4] = {wv[s].x, wv[s].y, wv[s].z, wv[s].w};
        ushort4 wh4, wl4;
        unsigned short* pwh = (unsigned short*)&wh4;
        unsigned short* pwl = (unsigned short*)&wl4;
#pragma unroll
        for (int e = 0; e < 4; ++e) {
          const unsigned short h2 = bf16_rne(fw[e]);
          pwh[e] = h2;
          pwl[e] = bf16_rne(fw[e] - bf16_val(h2));
        }
        *(ushort4*)&Bh[srow * LDT + kk] = wh4;
        *(ushort4*)&Bl[srow * LDT + kk] = wl4;
      }
    }
    __syncthreads();  // tile ready

    // ---- fragments + MFMA (layout m89-verified)
    bf16x8 afh[4], afl[4], bfh[4], bfl[4];
#pragma unroll
    for (int i = 0; i < 4; ++i) {
      const int ar = wr * 64 + i * 16 + lrow;
      afh[i] = *(const bf16x8*)&Ah[ar * LDT + lkg * 8];
      afl[i] = *(const bf16x8*)&Al[ar * LDT + lkg * 8];
      const int br = wc * 64 + i * 16 + lrow;
      bfh[i] = *(const bf16x8*)&Bh[br * LDT + lkg * 8];
      bfl[i] = *(const bf16x8*)&Bl[br * LDT + lkg * 8];
    }
#pragma unroll
    for (int i = 0; i < 4; ++i)
#pragma unroll
      for (int j = 0; j < 4; ++j) {
        acc[i][j] = __builtin_amdgcn_mfma_f32_16x16x32_bf16(afh[i], bfh[j], acc[i][j], 0, 0, 0);
        acc[i][j] = __builtin_amdgcn_mfma_f32_16x16x32_bf16(afh[i], bfl[j], acc[i][j], 0, 0, 0);
        acc[i][j] = __builtin_amdgcn_mfma_f32_16x16x32_bf16(afl[i], bfh[j], acc[i][j], 0, 0, 0);
      }
  }

  // ---- epilogue: C/D layout col=lane&15, row=(lane>>4)*4+reg
  const int rb = (lane >> 4) * 4;
#pragma unroll
  for (int j = 0; j < 4; ++j) {
    const int col = n0 + wc * 64 + j * 16 + lrow;
    const float bv = bias[col];
#pragma unroll
    for (int i = 0; i < 4; ++i) {
      const int row0 = m0 + wr * 64 + i * 16 + rb;
#pragma unroll
      for (int r = 0; r < 4; ++r) {
        const float v = acc[i][j][r] + bv;
        if constexpr (OUTTILED) {
          const int m = row0 + r;
          const int b = m >> 11, t = m & 2047;
          C[((size_t)(b * 8 + (col >> 6)) * TT + t) * 64 + (col & 63)] = v;
        } else {
          C[(size_t)(row0 + r) * HH + col] = v;
        }
      }
    }
  }
}

// ---------------------------------------------------------------------------
// Tiled diagonal scan: h_t = relu(pre_t + w[h]*h_{t-1}).
// Block = (b, hb): 64 h-columns; input TILED so each 16-t chunk is one
// contiguous 4KB region -> 4 x global_load_lds dwordx4.
// vmem ops/iter = 4 loads + 16 stores = 20. Issue order:
//   [L0 L1 L2] iter c: L(c+3), wait, compute, S(c).
// Ops newer than L(c): S(c-3),L(c+1),S(c-2),L(c+2),S(c-1),L(c+3) = 60
// -> vmcnt(60) guarantees L(c) landed with 3 chunks in flight.
// Ramp: c=0->12, c=1->28, c=2->44. Tail (c>=NCH-3): <=56 newer ops exist,
// so vmcnt(60) would pass early -> use 44 (stricter, safe).
// PACK: store u32 (bf16hi<<16 | bf16lo) TILED (feeds GEMM1 MODE3);
// else store fp32 to row-major d_out [b][t][h].
// ---------------------------------------------------------------------------
template <bool PACK>
__global__ __launch_bounds__(64) void indrnn_scan_tiled(
    const float* __restrict__ in, const float* __restrict__ w_hh,
    float* __restrict__ outf, unsigned* __restrict__ outp) {
  constexpr int CH = 16, NCH = TT / CH;
  __shared__ float lds[4 * CH * 64];
  const int lane = threadIdx.x;
  const int b = blockIdx.x >> 3, hb = blockIdx.x & 7;
  const size_t tilebase = (size_t)(b * 8 + hb) * TT * 64;  // elem units

  const float w = w_hh[hb * 64 + lane];
  float hv = 0.f;

  auto issue = [&](int c) {
    const float* cb = in + tilebase + (size_t)c * CH * 64;
    float* l = &lds[(c & 3) * (CH * 64)];
#pragma unroll
    for (int k = 0; k < 4; ++k) {
      // per-lane global addr; LDS ptr wave-uniform (HW adds lane*16)
      gload_lds16(cb + k * 256 + (lane >> 4) * 64 + (lane & 15) * 4, l + k * 256);
    }
  };

  issue(0);
  issue(1);
  issue(2);
  for (int c = 0; c < NCH; ++c) {
    if (c + 3 < NCH) issue(c + 3);
    if (c == 0)
      asm volatile("s_waitcnt vmcnt(12)" ::: "memory");
    else if (c == 1)
      asm volatile("s_waitcnt vmcnt(28)" ::: "memory");
    else if (c == 2 || c >= NCH - 3)
      asm volatile("s_waitcnt vmcnt(44)" ::: "memory");
    else
      asm volatile("s_waitcnt vmcnt(60)" ::: "memory");
    __builtin_amdgcn_sched_barrier(0);
    const float* l = &lds[(c & 3) * (CH * 64)];
#pragma unroll
    for (int tt = 0; tt < CH; ++tt) {
      const float p = l[tt * 64 + lane];
      hv = fmaxf(fmaf(w, hv, p), 0.f);
      if constexpr (PACK) {
        const unsigned short hi = bf16_rne(hv);
        const unsigned short lo = bf16_rne(hv - bf16_val(hi));
        outp[tilebase + (size_t)(c * CH + tt) * 64 + lane] =
            ((unsigned)hi << 16) | (unsigned)lo;
      } else {
        outf[((size_t)b * TT + c * CH + tt) * HH + hb * 64 + lane] = hv;
      }
    }
  }
}

// ---------------------------------------------------------------------------
// Tier-B strided scan (round-8 proven fallback).
// ---------------------------------------------------------------------------
__global__ __launch_bounds__(64) void indrnn_scan_strided(
    const float* __restrict__ pre, const float* __restrict__ w_hh,
    float* __restrict__ outf) {
  constexpr int CH = 16, NCH = TT / CH, AHEAD = 3;
  __shared__ float lds[4 * CH * 64];
  const int lane = threadIdx.x;
  const int gid = blockIdx.x * 64 + lane;
  const int h = gid & (HH - 1);
  const size_t colbase = (size_t)(gid >> 9) * TT * HH + h;

  const float w = w_hh[h];
  float hv = 0.f;

  auto issue = [&](int c) {
    const float* g = pre + colbase + (size_t)(c * CH) * HH;
    float* l = &lds[(c & 3) * CH * 64];
#pragma unroll
    for (int tt = 0; tt < CH; ++tt) gload_lds4(g + (size_t)tt * HH, l + tt * 64);
  };

  issue(0);
  issue(1);
  issue(2);
  for (int c = 0; c < NCH; ++c) {
    if (c + AHEAD < NCH) issue(c + AHEAD);
    asm volatile("s_waitcnt vmcnt(16)" ::: "memory");
    __builtin_amdgcn_sched_barrier(0);
    const float* l = &lds[(c & 3) * CH * 64];
#pragma unroll
    for (int tt = 0; tt < CH; ++tt) {
      const float p = l[tt * 64 + lane];
      hv = fmaxf(fmaf(w, hv, p), 0.f);
      outf[colbase + (size_t)(c * CH + tt) * HH] = hv;
    }
  }
}

// ---------------------------------------------------------------------------
__global__ __launch_bounds__(256) void convert_w(const float* __restrict__ W,
                                                 unsigned short* __restrict__ Wh,
                                                 unsigned short* __restrict__ Wl,
                                                 int n) {
  const int i = blockIdx.x * 256 + threadIdx.x;
  if (i < n) {
    const float f = W[i];
    const unsigned short hh = bf16_rne(f);
    Wh[i] = hh;
    Wl[i] = bf16_rne(f - bf16_val(hh));
  }
}

extern "C" void kernel_launch(void* const* d_in, const int* in_sizes, int n_in,
                              void* d_out, int out_size, void* d_ws, size_t ws_size,
                              hipStream_t stream) {
  const float* x     = (const float*)d_in[0];
  const float* w_ih0 = (const float*)d_in[1];
  const float* w_hh0 = (const float*)d_in[2];
  const float* b_ih0 = (const float*)d_in[3];
  const float* w_ih1 = (const float*)d_in[4];
  const float* w_hh1 = (const float*)d_in[5];
  const float* b_ih1 = (const float*)d_in[6];
  float* out = (float*)d_out;
  float* pre0 = (float*)d_ws;  // 256MB tiled fp32 (Tier A) / row-major (Tier B)
  char* wsb = (char*)d_ws;

  const size_t OFF_A1P = 268435456ull;            // packed u32 tiled, 256MB
  const size_t OFF_W0H = OFF_A1P + 268435456ull;  // 512MB
  const size_t OFF_W0L = OFF_W0H + 262144ull;
  const size_t OFF_W1H = OFF_W0L + 262144ull;
  const size_t OFF_W1L = OFF_W1H + 524288ull;
  const size_t NEED = OFF_W1L + 524288ull;  // ~513.5MB

  const int ntiles = (MM / 128) * (HH / 128);  // 4096

  if (ws_size >= NEED) {
    unsigned* A1p = (unsigned*)(wsb + OFF_A1P);
    unsigned short* W0h = (unsigned short*)(wsb + OFF_W0H);
    unsigned short* W0l = (unsigned short*)(wsb + OFF_W0L);
    unsigned short* W1h = (unsigned short*)(wsb + OFF_W1H);
    unsigned short* W1l = (unsigned short*)(wsb + OFF_W1L);

    convert_w<<<(HH * II) / 256, 256, 0, stream>>>(w_ih0, W0h, W0l, HH * II);
    convert_w<<<(HH * HH) / 256, 256, 0, stream>>>(w_ih1, W1h, W1l, HH * HH);
    gemm_mfma<II, 1, true><<<ntiles, 256, 0, stream>>>(
        x, nullptr, nullptr, W0h, W0l, b_ih0, pre0);
    indrnn_scan_tiled<true><<<BB * 8, 64, 0, stream>>>(pre0, w_hh0, nullptr, A1p);
    gemm_mfma<HH, 3, true><<<ntiles, 256, 0, stream>>>(
        nullptr, A1p, nullptr, W1h, W1l, b_ih1, pre0);  // pre1 aliases pre0
    indrnn_scan_tiled<false><<<BB * 8, 64, 0, stream>>>(pre0, w_hh1, out, nullptr);
  } else {
    gemm_mfma<II, 0, false><<<ntiles, 256, 0, stream>>>(
        x, nullptr, w_ih0, nullptr, nullptr, b_ih0, pre0);
    indrnn_scan_strided<<<(BB * HH) / 64, 64, 0, stream>>>(pre0, w_hh0, pre0);
    gemm_mfma<HH, 0, false><<<ntiles, 256, 0, stream>>>(
        pre0, nullptr, w_ih1, nullptr, nullptr, b_ih1, out);
    indrnn_scan_strided<<<(BB * HH) / 64, 64, 0, stream>>>(out, w_hh1, out);
  }
}